// Round 2
// baseline (3770.058 us; speedup 1.0000x reference)
//
#include <hip/hip_runtime.h>

// EdgeConv: B=4, C=64, N=8192, K=16, COUT=64, fp32.
// ws layout (needs ~27.6 MB):
//   xt    : 0         (B*N*C f32 = 8388608 B)   x transposed to (B,N,C)
//   knn   : 8388608   (B*N*16 i32 = 2097152 B)
//   mnb   : 10485760  (B*N*64 f32 = 8388608 B)  min_k h
//   mxb   : 18874368  (B*N*64 f32 = 8388608 B)  max_k h
//   ps1   : 27262976  (512*64 f32 = 131072 B)   per-block sum h
//   ps2   : 27394048  (512*64 f32 = 131072 B)   per-block sum h^2
//   stats : 27525120  (128 f32)                 mean[64], var[64]

#define Bn 4
#define Cn 64
#define Nn 8192
#define Kn 16
#define TILE 512
#define BUF 8

typedef unsigned long long ull;

// ---------------- transpose x (B,C,N) -> xt (B,N,C) ----------------
__global__ __launch_bounds__(256) void transpose_kernel(const float* __restrict__ x,
                                                        float* __restrict__ xt) {
  __shared__ float tile[64][65];
  int bid = blockIdx.x;          // 512 = B * (N/64)
  int b = bid >> 7;
  int n0 = (bid & 127) << 6;
  int tx = threadIdx.x & 63;
  int ty = threadIdx.x >> 6;
  for (int c = ty; c < 64; c += 4)
    tile[tx][c] = x[((size_t)b * 64 + c) * Nn + n0 + tx];
  __syncthreads();
  for (int r = ty; r < 64; r += 4)
    xt[((size_t)b * Nn + n0 + r) * 64 + tx] = tile[r][tx];
}

// ---------------- brute-force KNN (top-16 excluding self) ----------------
// d2 computed EXACTLY like the reference: (sq_n + sq_m) - 2*dot, with
// non-contracted f32 ops (__f*_rn) so rounding matches numpy's naive
// einsum (no FMA). Sort key = (f32_bits(d2) << 32) | index: stable
// lowest-index-first tie-break like lax.top_k. d2 >= 0 for distinct
// random points, so float-bit ordering == value ordering.
// block = 256 threads = 64 queries x 4 candidate-slices; grid = 512.

#define INSERT64(kv) do {                                     \
    ull _kk = (kv);                                           \
    bool _ci = _kk < ad[15];                                  \
    _Pragma("unroll")                                         \
    for (int _u = 15; _u >= 1; --_u) {                        \
      bool _cm = _kk < ad[_u - 1];                            \
      ull _nd = _cm ? ad[_u - 1] : _kk;                       \
      ad[_u] = _ci ? _nd : ad[_u];                            \
      _ci = _cm;                                              \
    }                                                         \
    ad[0] = _ci ? _kk : ad[0];                                \
    thr = ad[15];                                             \
  } while (0)

#define FLUSH do {                                            \
    for (int _t = 0; _t < bc; ++_t) {                         \
      ull _fk = fifo_k[tid][_t];                              \
      if (_fk < thr) INSERT64(_fk);                           \
    }                                                         \
    bc = 0;                                                   \
  } while (0)

__global__ __launch_bounds__(256) void knn_kernel(const float* __restrict__ coords,
                                                  int* __restrict__ knn) {
  __shared__ float4 ctile[TILE];          // 8 KB  (x,y,z,sq)
  __shared__ ull fifo_k[256][BUF];        // 16 KB
  __shared__ ull mk[64][3][16];           // 24 KB

  int bid = blockIdx.x;
  int b = bid >> 7;
  int q0 = (bid & 127) << 6;
  int tid = threadIdx.x;
  int q = tid & 63;
  int s = tid >> 6;                       // slice 0..3
  int qg = q0 + q;                        // query index within batch

  const float* cb = coords + (size_t)b * 3 * Nn;
  float qx = cb[qg], qy = cb[Nn + qg], qz = cb[2 * Nn + qg];
  // sq exactly as np.sum(ct*ct,-1): ((x*x + y*y) + z*z), no FMA
  float qs = __fadd_rn(__fadd_rn(__fmul_rn(qx, qx), __fmul_rn(qy, qy)),
                       __fmul_rn(qz, qz));

  ull ad[16];
#pragma unroll
  for (int i = 0; i < 16; ++i) ad[i] = 0xFFFFFFFFFFFFFFFFull;
  ull thr = 0xFFFFFFFFFFFFFFFFull;
  int bc = 0;

  for (int t = 0; t < Nn / TILE; ++t) {
    __syncthreads();
    for (int i = tid; i < TILE; i += 256) {
      int m = t * TILE + i;
      float cx = cb[m], cy = cb[Nn + m], cz = cb[2 * Nn + m];
      float cs = __fadd_rn(__fadd_rn(__fmul_rn(cx, cx), __fmul_rn(cy, cy)),
                           __fmul_rn(cz, cz));
      ctile[i] = make_float4(cx, cy, cz, cs);
    }
    __syncthreads();
    int jb = s * (TILE / 4);
    for (int j = 0; j < TILE / 4; ++j) {
      float4 c4 = ctile[jb + j];
      // dot exactly as np.einsum inner loop: ((qx*cx + qy*cy) + qz*cz)
      float dot = __fadd_rn(__fadd_rn(__fmul_rn(qx, c4.x), __fmul_rn(qy, c4.y)),
                            __fmul_rn(qz, c4.z));
      // d2 = (sq_n + sq_m) - 2*dot
      float d2 = __fsub_rn(__fadd_rn(qs, c4.w), __fmul_rn(2.0f, dot));
      int m = t * TILE + jb + j;
      ull key = ((ull)__float_as_uint(d2) << 32) | (unsigned)m;
      if (key < thr && m != qg) {
        fifo_k[tid][bc] = key; ++bc;
        if (bc == BUF) FLUSH;
      }
    }
  }
  FLUSH;

  // merge the 4 slices per query
  if (s > 0) {
#pragma unroll
    for (int i = 0; i < 16; ++i) mk[q][s - 1][i] = ad[i];
  }
  __syncthreads();
  if (s == 0) {
    for (int t = 0; t < 48; ++t) {
      ull kk = mk[q][t >> 4][t & 15];
      if (kk < thr) INSERT64(kk);
    }
    int* op = knn + (size_t)(b * Nn + qg) * 16;
#pragma unroll
    for (int i = 0; i < 16; ++i) op[i] = (int)(ad[i] & 0xFFFFFFFFull);
  }
}

// ---------------- edge features + GEMM + minmax + channel sums ----------------
// 1 wave per point batch (grid-stride). lane = cout. W columns in registers.
__global__ __launch_bounds__(256) void edge_kernel(
    const float* __restrict__ xt, const int* __restrict__ knn,
    const float* __restrict__ W, const float* __restrict__ bias,
    float* __restrict__ mnb, float* __restrict__ mxb,
    float* __restrict__ ps1, float* __restrict__ ps2) {
  __shared__ float dlds[4][16][64];   // per-wave diffs
  __shared__ float clds[4][64];       // per-wave center
  __shared__ float r1[4][64], r2[4][64];

  int tid = threadIdx.x;
  int l = tid & 63;
  int w = tid >> 6;

  float w1[64], w2[64];
#pragma unroll
  for (int c = 0; c < 64; ++c) {
    w1[c] = W[c * 64 + l];
    w2[c] = W[(64 + c) * 64 + l];
  }
  float bl = bias[l];
  float s1 = 0.f, s2 = 0.f;

  int wid = blockIdx.x * 4 + w;
  int nw = gridDim.x * 4;
  for (int p = wid; p < Bn * Nn; p += nw) {
    int bb = p >> 13;
    const float* xb = xt + (size_t)bb * Nn * 64;
    float ctr = xt[(size_t)p * 64 + l];
    clds[w][l] = ctr;
    const int* ip = knn + (size_t)p * 16;
#pragma unroll
    for (int j = 0; j < 16; ++j) {
      int nj = ip[j];
      dlds[w][j][l] = xb[(size_t)nj * 64 + l] - ctr;
    }
    __syncthreads();

    float cc = bl;
#pragma unroll
    for (int c = 0; c < 64; ++c) cc = fmaf(clds[w][c], w1[c], cc);

    float mn = 3.0e38f, mx = -3.0e38f;
#pragma unroll
    for (int k = 0; k < 16; ++k) {
      float h = cc;
#pragma unroll
      for (int c = 0; c < 64; ++c) h = fmaf(dlds[w][k][c], w2[c], h);
      mn = fminf(mn, h);
      mx = fmaxf(mx, h);
      s1 += h;
      s2 = fmaf(h, h, s2);
    }
    mnb[(size_t)p * 64 + l] = mn;
    mxb[(size_t)p * 64 + l] = mx;
    __syncthreads();
  }

  r1[w][l] = s1; r2[w][l] = s2;
  __syncthreads();
  if (w == 0) {
    float a = r1[0][l] + r1[1][l] + r1[2][l] + r1[3][l];
    float c2 = r2[0][l] + r2[1][l] + r2[2][l] + r2[3][l];
    ps1[blockIdx.x * 64 + l] = a;
    ps2[blockIdx.x * 64 + l] = c2;
  }
}

// ---------------- deterministic stats reduction ----------------
__global__ __launch_bounds__(256) void stats_kernel(const float* __restrict__ ps1,
                                                    const float* __restrict__ ps2,
                                                    float* __restrict__ stats) {
  __shared__ float r1[4][64], r2[4][64];
  int c = threadIdx.x & 63, g = threadIdx.x >> 6;
  float a = 0.f, b2 = 0.f;
  for (int i = g; i < 512; i += 4) { a += ps1[i * 64 + c]; b2 += ps2[i * 64 + c]; }
  r1[g][c] = a; r2[g][c] = b2;
  __syncthreads();
  if (g == 0) {
    float s1 = r1[0][c] + r1[1][c] + r1[2][c] + r1[3][c];
    float s2 = r2[0][c] + r2[1][c] + r2[2][c] + r2[3][c];
    const float invM = 1.f / 524288.f;  // B*N*K
    float mean = s1 * invM;
    float var = s2 * invM - mean * mean;
    stats[c] = mean;
    stats[64 + c] = var;
  }
}

// ---------------- finalize: normalize+relu+max_k, transposed store ----------------
__global__ __launch_bounds__(256) void final_kernel(
    const float* __restrict__ mnb, const float* __restrict__ mxb,
    const float* __restrict__ stats, const float* __restrict__ gamma,
    const float* __restrict__ beta, float* __restrict__ out) {
  __shared__ float tile[64][65];
  int bid = blockIdx.x;
  int b = bid >> 7;
  int n0 = (bid & 127) << 6;
  int tx = threadIdx.x & 63, ty = threadIdx.x >> 6;
  float mean = stats[tx], var = stats[64 + tx];
  float sc = gamma[tx] * rsqrtf(var + 1e-5f);
  float sh = fmaf(-mean, sc, beta[tx]);
  for (int r = ty; r < 64; r += 4) {
    size_t off = ((size_t)(b * Nn + n0 + r)) * 64 + tx;
    float lo = fmaf(mnb[off], sc, sh);
    float hi = fmaf(mxb[off], sc, sh);
    // max_k relu(sc*h+sh) == max(relu(sc*maxh+sh), relu(sc*minh+sh)) for any sc sign
    tile[tx][r] = fmaxf(fmaxf(hi, lo), 0.f);
  }
  __syncthreads();
  for (int r = ty; r < 64; r += 4)
    out[((size_t)b * 64 + r) * Nn + n0 + tx] = tile[r][tx];
}

extern "C" void kernel_launch(void* const* d_in, const int* in_sizes, int n_in,
                              void* d_out, int out_size, void* d_ws, size_t ws_size,
                              hipStream_t stream) {
  const float* x      = (const float*)d_in[0];
  const float* coords = (const float*)d_in[1];
  const float* W      = (const float*)d_in[2];
  const float* bias   = (const float*)d_in[3];
  const float* gamma  = (const float*)d_in[4];
  const float* beta   = (const float*)d_in[5];
  float* out = (float*)d_out;

  char* ws = (char*)d_ws;
  float* xt    = (float*)ws;
  int*   knn   = (int*)(ws + 8388608);
  float* mnb   = (float*)(ws + 10485760);
  float* mxb   = (float*)(ws + 18874368);
  float* ps1   = (float*)(ws + 27262976);
  float* ps2   = (float*)(ws + 27394048);
  float* stats = (float*)(ws + 27525120);

  transpose_kernel<<<dim3(512), dim3(256), 0, stream>>>(x, xt);
  knn_kernel<<<dim3(512), dim3(256), 0, stream>>>(coords, knn);
  edge_kernel<<<dim3(512), dim3(256), 0, stream>>>(xt, knn, W, bias, mnb, mxb, ps1, ps2);
  stats_kernel<<<dim3(1), dim3(256), 0, stream>>>(ps1, ps2, stats);
  final_kernel<<<dim3(512), dim3(256), 0, stream>>>(mnb, mxb, stats, gamma, beta, out);
}

// Round 5
// 587.877 us; speedup vs baseline: 6.4130x; 6.4130x over previous
//
#include <hip/hip_runtime.h>

// EdgeConv: B=4, C=64, N=8192, K=16, COUT=64, fp32.
// ws layout (needs ~27.6 MB):
//   xt    : 0         (B*N*C f32 = 8388608 B)   x transposed to (B,N,C)
//   knn   : 8388608   (B*N*16 i32 = 2097152 B)
//   mnb   : 10485760  (B*N*64 f32 = 8388608 B)  min_k h
//   mxb   : 18874368  (B*N*64 f32 = 8388608 B)  max_k h
//   ps1   : 27262976  (512*64 f32 = 131072 B)   per-block sum h
//   ps2   : 27394048  (512*64 f32 = 131072 B)   per-block sum h^2
//   stats : 27525120  (128 f32)                 mean[64], var[64]

#define Bn 4
#define Cn 64
#define Nn 8192
#define Kn 16
#define TILE 512
#define CH 32

typedef unsigned long long ull;

// ---------------- transpose x (B,C,N) -> xt (B,N,C) ----------------
__global__ __launch_bounds__(256) void transpose_kernel(const float* __restrict__ x,
                                                        float* __restrict__ xt) {
  __shared__ float tile[64][65];
  int bid = blockIdx.x;          // 512 = B * (N/64)
  int b = bid >> 7;
  int n0 = (bid & 127) << 6;
  int tx = threadIdx.x & 63;
  int ty = threadIdx.x >> 6;
  for (int c = ty; c < 64; c += 4)
    tile[tx][c] = x[((size_t)b * 64 + c) * Nn + n0 + tx];
  __syncthreads();
  for (int r = ty; r < 64; r += 4)
    xt[((size_t)b * Nn + n0 + r) * 64 + tx] = tile[r][tx];
}

// ---------------- brute-force KNN (top-16 excluding self) ----------------
// d2 EXACTLY like the reference: (sq_n + sq_m) - 2*dot, non-contracted f32.
// 2*dot folded as dot2 with pre-doubled query coords (pow2 scaling commutes
// with rounding -> bit-identical). Sort key = (f32_bits(d2)<<32)|idx: stable
// lowest-index tie-break like lax.top_k (d2 >= 0 so bit order == value order).
//
// Divergence fix vs r1: scan in chunks of CH=32 with a branchless u32 accept
// test against a (stale) threshold; accepts go to LDS fifo [slot][tid]
// (lane-consecutive, conflict-free); the expensive 16-deep sorted insert runs
// once per chunk, wave-synchronized (divergent bc loop = max_bc iterations).
// Chunk size == fifo depth -> no overflow even with thr = +inf in pass 0.

#define INSERT64(kv) do {                                     \
    ull _kk = (kv);                                           \
    bool _ci = _kk < ad[15];                                  \
    _Pragma("unroll")                                         \
    for (int _u = 15; _u >= 1; --_u) {                        \
      bool _cm = _kk < ad[_u - 1];                            \
      ull _nd = _cm ? ad[_u - 1] : _kk;                       \
      ad[_u] = _ci ? _nd : ad[_u];                            \
      _ci = _cm;                                              \
    }                                                         \
    ad[0] = _ci ? _kk : ad[0];                                \
    thr = ad[15];                                             \
  } while (0)

__global__ __launch_bounds__(256) void knn_kernel(const float* __restrict__ coords,
                                                  int* __restrict__ knn) {
  __shared__ float4 ctile[TILE];              // 8 KB (x,y,z,sq)
  __shared__ unsigned fifo_d[CH * 256];       // 32 KB (d2 bits; merge reuses)
  __shared__ unsigned fifo_i[CH * 256];       // 32 KB (index;   merge reuses)

  int bid = blockIdx.x;
  int b = bid >> 7;
  int q0 = (bid & 127) << 6;
  int tid = threadIdx.x;
  int q = tid & 63;
  int s = tid >> 6;                       // slice 0..3
  int qg = q0 + q;                        // query index within batch

  const float* cb = coords + (size_t)b * 3 * Nn;
  float qx = cb[qg], qy = cb[Nn + qg], qz = cb[2 * Nn + qg];
  // sq exactly as np.sum(ct*ct,-1): ((x*x + y*y) + z*z), no FMA
  float qs = __fadd_rn(__fadd_rn(__fmul_rn(qx, qx), __fmul_rn(qy, qy)),
                       __fmul_rn(qz, qz));
  float qx2 = 2.f * qx, qy2 = 2.f * qy, qz2 = 2.f * qz;

  ull ad[16];
#pragma unroll
  for (int i = 0; i < 16; ++i) ad[i] = ~0ull;
  ull thr = ~0ull;
  unsigned thr_hi = 0xFFFFFFFFu;
  int bc = 0;

  for (int t = 0; t < Nn / TILE; ++t) {
    __syncthreads();
    for (int i = tid; i < TILE; i += 256) {
      int m = t * TILE + i;
      float cx = cb[m], cy = cb[Nn + m], cz = cb[2 * Nn + m];
      float cs = __fadd_rn(__fadd_rn(__fmul_rn(cx, cx), __fmul_rn(cy, cy)),
                           __fmul_rn(cz, cz));
      ctile[i] = make_float4(cx, cy, cz, cs);
    }
    __syncthreads();
    int jb = s * (TILE / 4);
    for (int c = 0; c < (TILE / 4) / CH; ++c) {
#pragma unroll 8
      for (int j = 0; j < CH; ++j) {
        int ji = jb + c * CH + j;
        float4 c4 = ctile[ji];
        // dot2 = 2*((qx*cx + qy*cy) + qz*cz), bit-exact via pre-doubling
        float dot2 = __fadd_rn(__fadd_rn(__fmul_rn(qx2, c4.x), __fmul_rn(qy2, c4.y)),
                               __fmul_rn(qz2, c4.z));
        float d2 = __fsub_rn(__fadd_rn(qs, c4.w), dot2);
        int m = t * TILE + ji;
        unsigned bits = __float_as_uint(d2);
        // u32 compare (not float: empty-slot threshold bits are NaN);
        // <= admits boundary ties, insert resolves exactly on u64 key
        if (bits <= thr_hi && m != qg) {
          fifo_d[bc * 256 + tid] = bits;
          fifo_i[bc * 256 + tid] = (unsigned)m;
          ++bc;
        }
      }
      // wave-synchronized flush: runs max(bc) iterations, lanes exec-masked
      for (int u = 0; u < bc; ++u) {
        ull kk = ((ull)fifo_d[u * 256 + tid] << 32) | fifo_i[u * 256 + tid];
        if (kk < thr) INSERT64(kk);
      }
      bc = 0;
      thr_hi = (unsigned)(thr >> 32);
    }
  }

  // merge the 4 slices per query (reuse fifo LDS: 48*64 slots per array)
  __syncthreads();
  if (s > 0) {
#pragma unroll
    for (int i = 0; i < 16; ++i) {
      int slot = ((((s - 1) << 4) + i) << 6) + q;
      fifo_d[slot] = (unsigned)(ad[i] >> 32);
      fifo_i[slot] = (unsigned)(ad[i] & 0xFFFFFFFFull);
    }
  }
  __syncthreads();
  if (s == 0) {
    for (int t = 0; t < 48; ++t) {
      int slot = (t << 6) + q;
      ull kk = ((ull)fifo_d[slot] << 32) | fifo_i[slot];
      if (kk < thr) INSERT64(kk);
    }
    int* op = knn + (size_t)(b * Nn + qg) * 16;
#pragma unroll
    for (int i = 0; i < 16; ++i) op[i] = (int)(ad[i] & 0xFFFFFFFFull);
  }
}

// ---------------- edge features + GEMM + minmax + channel sums ----------------
// 1 wave per point batch (grid-stride). lane = cout. W columns in registers.
__global__ __launch_bounds__(256) void edge_kernel(
    const float* __restrict__ xt, const int* __restrict__ knn,
    const float* __restrict__ W, const float* __restrict__ bias,
    float* __restrict__ mnb, float* __restrict__ mxb,
    float* __restrict__ ps1, float* __restrict__ ps2) {
  __shared__ float dlds[4][16][64];   // per-wave diffs
  __shared__ float clds[4][64];       // per-wave center
  __shared__ float r1[4][64], r2[4][64];

  int tid = threadIdx.x;
  int l = tid & 63;
  int w = tid >> 6;

  float w1[64], w2[64];
#pragma unroll
  for (int c = 0; c < 64; ++c) {
    w1[c] = W[c * 64 + l];
    w2[c] = W[(64 + c) * 64 + l];
  }
  float bl = bias[l];
  float s1 = 0.f, s2 = 0.f;

  int wid = blockIdx.x * 4 + w;
  int nw = gridDim.x * 4;
  for (int p = wid; p < Bn * Nn; p += nw) {
    int bb = p >> 13;
    const float* xb = xt + (size_t)bb * Nn * 64;
    float ctr = xt[(size_t)p * 64 + l];
    clds[w][l] = ctr;
    const int* ip = knn + (size_t)p * 16;
#pragma unroll
    for (int j = 0; j < 16; ++j) {
      int nj = ip[j];
      dlds[w][j][l] = xb[(size_t)nj * 64 + l] - ctr;
    }
    __syncthreads();

    float cc = bl;
#pragma unroll
    for (int c = 0; c < 64; ++c) cc = fmaf(clds[w][c], w1[c], cc);

    float mn = 3.0e38f, mx = -3.0e38f;
#pragma unroll
    for (int k = 0; k < 16; ++k) {
      float h = cc;
#pragma unroll
      for (int c = 0; c < 64; ++c) h = fmaf(dlds[w][k][c], w2[c], h);
      mn = fminf(mn, h);
      mx = fmaxf(mx, h);
      s1 += h;
      s2 = fmaf(h, h, s2);
    }
    mnb[(size_t)p * 64 + l] = mn;
    mxb[(size_t)p * 64 + l] = mx;
    __syncthreads();
  }

  r1[w][l] = s1; r2[w][l] = s2;
  __syncthreads();
  if (w == 0) {
    float a = r1[0][l] + r1[1][l] + r1[2][l] + r1[3][l];
    float c2 = r2[0][l] + r2[1][l] + r2[2][l] + r2[3][l];
    ps1[blockIdx.x * 64 + l] = a;
    ps2[blockIdx.x * 64 + l] = c2;
  }
}

// ---------------- deterministic stats reduction ----------------
__global__ __launch_bounds__(256) void stats_kernel(const float* __restrict__ ps1,
                                                    const float* __restrict__ ps2,
                                                    float* __restrict__ stats) {
  __shared__ float r1[4][64], r2[4][64];
  int c = threadIdx.x & 63, g = threadIdx.x >> 6;
  float a = 0.f, b2 = 0.f;
  for (int i = g; i < 512; i += 4) { a += ps1[i * 64 + c]; b2 += ps2[i * 64 + c]; }
  r1[g][c] = a; r2[g][c] = b2;
  __syncthreads();
  if (g == 0) {
    float s1 = r1[0][c] + r1[1][c] + r1[2][c] + r1[3][c];
    float s2 = r2[0][c] + r2[1][c] + r2[2][c] + r2[3][c];
    const float invM = 1.f / 524288.f;  // B*N*K
    float mean = s1 * invM;
    float var = s2 * invM - mean * mean;
    stats[c] = mean;
    stats[64 + c] = var;
  }
}

// ---------------- finalize: normalize+relu+max_k, transposed store ----------------
__global__ __launch_bounds__(256) void final_kernel(
    const float* __restrict__ mnb, const float* __restrict__ mxb,
    const float* __restrict__ stats, const float* __restrict__ gamma,
    const float* __restrict__ beta, float* __restrict__ out) {
  __shared__ float tile[64][65];
  int bid = blockIdx.x;
  int b = bid >> 7;
  int n0 = (bid & 127) << 6;
  int tx = threadIdx.x & 63, ty = threadIdx.x >> 6;
  float mean = stats[tx], var = stats[64 + tx];
  float sc = gamma[tx] * rsqrtf(var + 1e-5f);
  float sh = fmaf(-mean, sc, beta[tx]);
  for (int r = ty; r < 64; r += 4) {
    size_t off = ((size_t)(b * Nn + n0 + r)) * 64 + tx;
    float lo = fmaf(mnb[off], sc, sh);
    float hi = fmaf(mxb[off], sc, sh);
    // max_k relu(sc*h+sh) == max(relu(sc*maxh+sh), relu(sc*minh+sh)) for any sc sign
    tile[tx][r] = fmaxf(fmaxf(hi, lo), 0.f);
  }
  __syncthreads();
  for (int r = ty; r < 64; r += 4)
    out[((size_t)b * 64 + r) * Nn + n0 + tx] = tile[r][tx];
}

extern "C" void kernel_launch(void* const* d_in, const int* in_sizes, int n_in,
                              void* d_out, int out_size, void* d_ws, size_t ws_size,
                              hipStream_t stream) {
  const float* x      = (const float*)d_in[0];
  const float* coords = (const float*)d_in[1];
  const float* W      = (const float*)d_in[2];
  const float* bias   = (const float*)d_in[3];
  const float* gamma  = (const float*)d_in[4];
  const float* beta   = (const float*)d_in[5];
  float* out = (float*)d_out;

  char* ws = (char*)d_ws;
  float* xt    = (float*)ws;
  int*   knn   = (int*)(ws + 8388608);
  float* mnb   = (float*)(ws + 10485760);
  float* mxb   = (float*)(ws + 18874368);
  float* ps1   = (float*)(ws + 27262976);
  float* ps2   = (float*)(ws + 27394048);
  float* stats = (float*)(ws + 27525120);

  transpose_kernel<<<dim3(512), dim3(256), 0, stream>>>(x, xt);
  knn_kernel<<<dim3(512), dim3(256), 0, stream>>>(coords, knn);
  edge_kernel<<<dim3(512), dim3(256), 0, stream>>>(xt, knn, W, bias, mnb, mxb, ps1, ps2);
  stats_kernel<<<dim3(1), dim3(256), 0, stream>>>(ps1, ps2, stats);
  final_kernel<<<dim3(512), dim3(256), 0, stream>>>(mnb, mxb, stats, gamma, beta, out);
}